// Round 1
// baseline (495.039 us; speedup 1.0000x reference)
//
#include <hip/hip_runtime.h>
#include <math.h>

#define B_ 8
#define D_ 1024
#define HW_ 4096
#define NH_ 16
#define EPS_ 1e-5f

// workspace offsets (in floats)
#define PE_OFF   0u          // 4096*1024
#define Q0_OFF   4194304u    // B*D
#define VCLS_OFF 4202496u    // B*D
#define UT_OFF   4210688u    // B*D*NH   u_t[b][d][h] (scale folded in)
#define TB_OFF   4341760u    // B*D
#define SC_OFF   4349952u    // B*NH*HW  scores for tokens
#define PT_OFF   4874240u    // B*NH*HW  probs for tokens
#define P0_OFF   5398528u    // B*NH     prob of cls token
#define W_OFF    5398656u    // B*NH*D   weighted sum of xc
#define CLS_OFF  5529728u    // B*D
#define R0_OFF   5537920u    // B*D

// ---------------- K0: positional encoding table, pe_t[d][p] ----------------
__global__ void k_pe(float* __restrict__ pe) {
    int idx = blockIdx.x * 256 + threadIdx.x;   // idx = d*HW + p
    int p = idx & (HW_ - 1);
    int d = idx >> 12;
    float e = (float)(2 * (d >> 1));
    float rate = exp2f(e * (-13.287712379549449f / 1024.0f)); // 10000^(-e/1024)
    float ang = (float)p * rate;
    float s, c;
    sincosf(ang, &s, &c);
    pe[idx] = (d & 1) ? c : s;
}

// ---------------- K1: q0[b,:] and v_cls[b,:] (wave per output row) ---------
__global__ void k_qv(const float* __restrict__ Wqkv, const float* __restrict__ bqkv,
                     const float* __restrict__ ctx,
                     float* __restrict__ q0, float* __restrict__ vcls) {
    int wid  = (blockIdx.x * 256 + threadIdx.x) >> 6;  // 0..16383
    int lane = threadIdx.x & 63;
    int isv  = wid >> 13;          // 0: q row, 1: v row
    int r    = wid & 8191;
    int b = r >> 10, i = r & 1023;
    int row = isv ? (2 * D_ + i) : i;
    const float4* wr = (const float4*)(Wqkv + (size_t)row * D_);
    const float4* cb = (const float4*)(ctx + b * D_);
    float acc = 0.0f;
    for (int k = lane; k < 256; k += 64) {
        float4 a = wr[k], c = cb[k];
        acc += a.x * c.x + a.y * c.y + a.z * c.z + a.w * c.w;
    }
    for (int o = 32; o; o >>= 1) acc += __shfl_down(acc, o);
    if (lane == 0) {
        float v = acc + bqkv[row];
        if (isv) vcls[b * D_ + i] = v; else q0[b * D_ + i] = v;
    }
}

// ---------------- K2: u_t[b][d][h] (scale folded) and t_b[b][i] ------------
__global__ void k_u_tb(const float* __restrict__ Wqkv,
                       const float* __restrict__ Wo, const float* __restrict__ bo,
                       const float* __restrict__ q0, const float* __restrict__ vcls,
                       float* __restrict__ u_t, float* __restrict__ t_b) {
    if (blockIdx.x < 128) {
        int b = blockIdx.x >> 4, h = blockIdx.x & 15;
        int t = threadIdx.x;  // 256 threads
        float a0 = 0, a1 = 0, a2 = 0, a3 = 0;
        const float* q0h = q0 + b * D_ + h * 64;
        for (int j = 0; j < 64; ++j) {
            float qj = q0h[j];
            const float* wr = Wqkv + (size_t)(D_ + h * 64 + j) * D_;
            a0 += qj * wr[t];
            a1 += qj * wr[t + 256];
            a2 += qj * wr[t + 512];
            a3 += qj * wr[t + 768];
        }
        float* ub = u_t + (size_t)(b * D_) * NH_ + h;
        ub[(size_t)t * 16]          = 0.125f * a0;
        ub[(size_t)(t + 256) * 16]  = 0.125f * a1;
        ub[(size_t)(t + 512) * 16]  = 0.125f * a2;
        ub[(size_t)(t + 768) * 16]  = 0.125f * a3;
    } else {
        int wid  = (blockIdx.x - 128) * 4 + (threadIdx.x >> 6); // 0..8191
        int lane = threadIdx.x & 63;
        int b = wid >> 10, i = wid & 1023;
        const float4* wr = (const float4*)(Wo + (size_t)i * D_);
        const float4* vb = (const float4*)(vcls + b * D_);
        float acc = 0.0f;
        for (int k = lane; k < 256; k += 64) {
            float4 a = wr[k], c = vb[k];
            acc += a.x * c.x + a.y * c.y + a.z * c.z + a.w * c.w;
        }
        for (int o = 32; o; o >>= 1) acc += __shfl_down(acc, o);
        if (lane == 0) t_b[b * D_ + i] = acc + bo[i];
    }
}

// ------- KB: fused token scores + LayerNorm feature-map output -------------
// grid (HW/64, B), block 512 (8 waves). wave w covers d in [w*128, w*128+128);
// lane l <-> position p = blockIdx.x*64 + l.
__global__ __launch_bounds__(512) void k_main(
        const float* __restrict__ x, const float* __restrict__ pe,
        const float* __restrict__ u_t, const float* __restrict__ t_b,
        const float* __restrict__ gamma, const float* __restrict__ beta,
        float* __restrict__ scores, float* __restrict__ out) {
    int wave = threadIdx.x >> 6, lane = threadIdx.x & 63;
    int b = blockIdx.y;
    int p = blockIdx.x * 64 + lane;
    const float* xb = x + (size_t)b * D_ * HW_;
    const float* tb = t_b + b * D_;
    float acc[16];
    #pragma unroll
    for (int h = 0; h < 16; ++h) acc[h] = 0.0f;
    float sum = 0.0f, sumsq = 0.0f;
    int d0 = wave * 128;
    for (int d = d0; d < d0 + 128; ++d) {
        float xv = xb[(size_t)d * HW_ + p];
        float pv = pe[(size_t)d * HW_ + p];
        float xc = xv + pv;
        float resv = xc + tb[d];
        sum += resv;
        sumsq += resv * resv;
        const float* up = u_t + (size_t)(b * D_ + d) * 16;
        #pragma unroll
        for (int h = 0; h < 16; ++h) acc[h] += up[h] * xc;
    }
    __shared__ float red[8][18][64];
    #pragma unroll
    for (int h = 0; h < 16; ++h) red[wave][h][lane] = acc[h];
    red[wave][16][lane] = sum;
    red[wave][17][lane] = sumsq;
    __syncthreads();
    // scores: 16 heads x 64 lanes = 1024 values, 512 threads -> 2 each
    for (int id = threadIdx.x; id < 1024; id += 512) {
        int h = id >> 6, l = id & 63;
        float s = 0.0f;
        #pragma unroll
        for (int w2 = 0; w2 < 8; ++w2) s += red[w2][h][l];
        scores[(size_t)(b * 16 + h) * HW_ + blockIdx.x * 64 + l] = s;
    }
    if (threadIdx.x < 64) {
        int l = threadIdx.x;
        float S = 0.0f, SQ = 0.0f;
        #pragma unroll
        for (int w2 = 0; w2 < 8; ++w2) { S += red[w2][16][l]; SQ += red[w2][17][l]; }
        float mu = S * (1.0f / D_);
        float var = SQ * (1.0f / D_) - mu * mu;
        red[0][16][l] = mu;
        red[0][17][l] = rsqrtf(var + EPS_);
    }
    __syncthreads();
    float mu = red[0][16][lane], rstd = red[0][17][lane];
    float* ob = out + (size_t)b * D_ * HW_;
    for (int d = d0; d < d0 + 128; ++d) {
        float resv = xb[(size_t)d * HW_ + p] + pe[(size_t)d * HW_ + p] + tb[d];
        ob[(size_t)d * HW_ + p] = (resv - mu) * rstd * gamma[d] + beta[d];
    }
}

// ---------------- K5: cls score + softmax over 4097 entries ----------------
__global__ void k_softmax(const float* __restrict__ scores, const float* __restrict__ u_t,
                          const float* __restrict__ ctx,
                          float* __restrict__ probs_tok, float* __restrict__ probs0) {
    int b = blockIdx.x >> 4, h = blockIdx.x & 15;
    int t = threadIdx.x;  // 256
    __shared__ float lds[256];
    // s0 = u . ctx  (bias term is uniform over s -> cancels in softmax)
    float part = 0.0f;
    for (int d = t; d < D_; d += 256)
        part += u_t[(size_t)(b * D_ + d) * 16 + h] * ctx[b * D_ + d];
    lds[t] = part; __syncthreads();
    for (int o = 128; o; o >>= 1) { if (t < o) lds[t] += lds[t + o]; __syncthreads(); }
    float s0 = lds[0];
    __syncthreads();
    const float4* sr = (const float4*)(scores + (size_t)(b * 16 + h) * HW_);
    float4 v[4];
    float m = s0;
    #pragma unroll
    for (int k = 0; k < 4; ++k) {
        v[k] = sr[t + 256 * k];
        m = fmaxf(m, fmaxf(fmaxf(v[k].x, v[k].y), fmaxf(v[k].z, v[k].w)));
    }
    lds[t] = m; __syncthreads();
    for (int o = 128; o; o >>= 1) { if (t < o) lds[t] = fmaxf(lds[t], lds[t + o]); __syncthreads(); }
    m = lds[0];
    __syncthreads();
    float zs = 0.0f;
    #pragma unroll
    for (int k = 0; k < 4; ++k) {
        v[k].x = expf(v[k].x - m); v[k].y = expf(v[k].y - m);
        v[k].z = expf(v[k].z - m); v[k].w = expf(v[k].w - m);
        zs += v[k].x + v[k].y + v[k].z + v[k].w;
    }
    float e0 = expf(s0 - m);
    lds[t] = zs; __syncthreads();
    for (int o = 128; o; o >>= 1) { if (t < o) lds[t] += lds[t + o]; __syncthreads(); }
    float inv = 1.0f / (lds[0] + e0);
    float4* pr = (float4*)(probs_tok + (size_t)(b * 16 + h) * HW_);
    #pragma unroll
    for (int k = 0; k < 4; ++k) {
        float4 o4 = v[k];
        o4.x *= inv; o4.y *= inv; o4.z *= inv; o4.w *= inv;
        pr[t + 256 * k] = o4;
    }
    if (t == 0) probs0[b * 16 + h] = e0 * inv;
}

// ---------------- K6: w[b][h][d] = sum_s probs * xc --------------------------
// grid (D/32, B), block 512 (8 waves); wave handles 4 d-rows, lanes stride p.
__global__ __launch_bounds__(512) void k_wacc(
        const float* __restrict__ x, const float* __restrict__ pe,
        const float* __restrict__ probs_tok, const float* __restrict__ probs0,
        const float* __restrict__ ctx, float* __restrict__ w) {
    int wave = threadIdx.x >> 6, lane = threadIdx.x & 63;
    int b = blockIdx.y;
    int d0 = blockIdx.x * 32 + wave * 4;
    const float* xb = x + (size_t)b * D_ * HW_;
    const float* pb = probs_tok + (size_t)b * 16 * HW_;
    float acc[4][16];
    #pragma unroll
    for (int r = 0; r < 4; ++r)
        #pragma unroll
        for (int h = 0; h < 16; ++h) acc[r][h] = 0.0f;
    for (int it = 0; it < 64; ++it) {
        int p = it * 64 + lane;
        float xv[4];
        #pragma unroll
        for (int r = 0; r < 4; ++r)
            xv[r] = xb[(size_t)(d0 + r) * HW_ + p] + pe[(size_t)(d0 + r) * HW_ + p];
        #pragma unroll
        for (int h = 0; h < 16; ++h) {
            float prv = pb[(size_t)h * HW_ + p];
            #pragma unroll
            for (int r = 0; r < 4; ++r) acc[r][h] += prv * xv[r];
        }
    }
    #pragma unroll
    for (int r = 0; r < 4; ++r)
        #pragma unroll
        for (int h = 0; h < 16; ++h) {
            float v = acc[r][h];
            for (int o = 32; o; o >>= 1) v += __shfl_down(v, o);
            acc[r][h] = v;
        }
    if (lane == 0) {
        #pragma unroll
        for (int h = 0; h < 16; ++h) {
            float p0 = probs0[b * 16 + h];
            #pragma unroll
            for (int r = 0; r < 4; ++r)
                w[(size_t)(b * 16 + h) * D_ + d0 + r] = acc[r][h] + p0 * ctx[b * D_ + d0 + r];
        }
    }
}

// ---------------- K7a: cls[b][i] = Wv[i,:] . w[b][i>>6][:] + bv -------------
__global__ void k_cls(const float* __restrict__ Wqkv, const float* __restrict__ bqkv,
                      const float* __restrict__ w, float* __restrict__ cls) {
    int wid  = (blockIdx.x * 256 + threadIdx.x) >> 6;  // 0..8191
    int lane = threadIdx.x & 63;
    int b = wid >> 10, i = wid & 1023, h = i >> 6;
    const float4* wr = (const float4*)(Wqkv + (size_t)(2 * D_ + i) * D_);
    const float4* wb = (const float4*)(w + (size_t)(b * 16 + h) * D_);
    float acc = 0.0f;
    for (int k = lane; k < 256; k += 64) {
        float4 a = wr[k], c = wb[k];
        acc += a.x * c.x + a.y * c.y + a.z * c.z + a.w * c.w;
    }
    for (int o = 32; o; o >>= 1) acc += __shfl_down(acc, o);
    if (lane == 0) cls[b * D_ + i] = acc + bqkv[2 * D_ + i];
}

// ---------------- K7b: res0 = Wo @ cls + bo + ctx ---------------------------
__global__ void k_attn0(const float* __restrict__ Wo, const float* __restrict__ bo,
                        const float* __restrict__ cls, const float* __restrict__ ctx,
                        float* __restrict__ res0) {
    int wid  = (blockIdx.x * 256 + threadIdx.x) >> 6;
    int lane = threadIdx.x & 63;
    int b = wid >> 10, i = wid & 1023;
    const float4* wr = (const float4*)(Wo + (size_t)i * D_);
    const float4* cb = (const float4*)(cls + b * D_);
    float acc = 0.0f;
    for (int k = lane; k < 256; k += 64) {
        float4 a = wr[k], c = cb[k];
        acc += a.x * c.x + a.y * c.y + a.z * c.z + a.w * c.w;
    }
    for (int o = 32; o; o >>= 1) acc += __shfl_down(acc, o);
    if (lane == 0) res0[b * D_ + i] = acc + bo[i] + ctx[b * D_ + i];
}

// ---------------- K7c: LayerNorm of res0 -> context_token_out ---------------
__global__ void k_ln0(const float* __restrict__ res0, const float* __restrict__ gamma,
                      const float* __restrict__ beta, float* __restrict__ out) {
    int b = blockIdx.x, t = threadIdx.x;  // 256 threads
    __shared__ float lds[512];
    float v[4];
    float s = 0.0f, sq = 0.0f;
    #pragma unroll
    for (int k = 0; k < 4; ++k) {
        v[k] = res0[b * D_ + t + 256 * k];
        s += v[k]; sq += v[k] * v[k];
    }
    lds[t] = s; lds[256 + t] = sq; __syncthreads();
    for (int o = 128; o; o >>= 1) {
        if (t < o) { lds[t] += lds[t + o]; lds[256 + t] += lds[256 + t + o]; }
        __syncthreads();
    }
    float mu = lds[0] * (1.0f / D_);
    float var = lds[256] * (1.0f / D_) - mu * mu;
    float rstd = rsqrtf(var + EPS_);
    #pragma unroll
    for (int k = 0; k < 4; ++k) {
        int i = t + 256 * k;
        out[(size_t)B_ * D_ * HW_ + b * D_ + i] = (v[k] - mu) * rstd * gamma[i] + beta[i];
    }
}

extern "C" void kernel_launch(void* const* d_in, const int* in_sizes, int n_in,
                              void* d_out, int out_size, void* d_ws, size_t ws_size,
                              hipStream_t stream) {
    const float* x     = (const float*)d_in[0];
    const float* ctx   = (const float*)d_in[1];
    const float* Wqkv  = (const float*)d_in[2];
    const float* bqkv  = (const float*)d_in[3];
    const float* Wo    = (const float*)d_in[4];
    const float* bo    = (const float*)d_in[5];
    const float* gamma = (const float*)d_in[6];
    const float* beta  = (const float*)d_in[7];
    float* out = (float*)d_out;
    float* ws  = (float*)d_ws;

    float* pe    = ws + PE_OFF;
    float* q0    = ws + Q0_OFF;
    float* vcls  = ws + VCLS_OFF;
    float* u_t   = ws + UT_OFF;
    float* t_b   = ws + TB_OFF;
    float* sc    = ws + SC_OFF;
    float* pt    = ws + PT_OFF;
    float* p0    = ws + P0_OFF;
    float* w     = ws + W_OFF;
    float* cls   = ws + CLS_OFF;
    float* r0    = ws + R0_OFF;

    k_pe<<<dim3(16384), dim3(256), 0, stream>>>(pe);
    k_qv<<<dim3(4096), dim3(256), 0, stream>>>(Wqkv, bqkv, ctx, q0, vcls);
    k_u_tb<<<dim3(2176), dim3(256), 0, stream>>>(Wqkv, Wo, bo, q0, vcls, u_t, t_b);
    k_main<<<dim3(64, 8), dim3(512), 0, stream>>>(x, pe, u_t, t_b, gamma, beta, sc, out);
    k_softmax<<<dim3(128), dim3(256), 0, stream>>>(sc, u_t, ctx, pt, p0);
    k_wacc<<<dim3(32, 8), dim3(512), 0, stream>>>(x, pe, pt, p0, ctx, w);
    k_cls<<<dim3(2048), dim3(256), 0, stream>>>(Wqkv, bqkv, w, cls);
    k_attn0<<<dim3(2048), dim3(256), 0, stream>>>(Wo, bo, cls, ctx, r0);
    k_ln0<<<dim3(8), dim3(256), 0, stream>>>(r0, gamma, beta, out);
}

// Round 2
// 429.016 us; speedup vs baseline: 1.1539x; 1.1539x over previous
//
#include <hip/hip_runtime.h>
#include <math.h>

#define B_ 8
#define D_ 1024
#define HW_ 4096
#define NH_ 16
#define EPS_ 1e-5f

// workspace offsets (in floats) — total 5,087,360 floats = 20.35 MB
#define PE_OFF   0u          // 4096*1024  pe[d][p]
#define UT_OFF   4194304u    // B*D*NH     u_t[b][d][h] (scale folded)
#define TB_OFF   4325376u    // B*D
#define SC_OFF   4333568u    // B*NH*HW    scores; softmax overwrites in place with probs
#define Q0_OFF   4857856u    // B*D
#define VCLS_OFF 4866048u    // B*D
#define P0_OFF   4874240u    // B*NH
#define MU_OFF   4874368u    // B*HW
#define RS_OFF   4907136u    // B*HW
#define W_OFF    4939904u    // B*NH*D
#define CLS_OFF  5070976u    // B*D
#define R0_OFF   5079168u    // B*D

// ---------------- K0: positional encoding table, pe[d][p]; sin/cos pairs ----
__global__ void k_pe(float* __restrict__ pe) {
    int idx = blockIdx.x * 256 + threadIdx.x;   // 0 .. 2^21-1
    int p  = idx & (HW_ - 1);
    int dp = idx >> 12;                          // d-pair 0..511
    float e = (float)(2 * dp);
    float rate = exp2f(e * (-13.287712379549449f / 1024.0f)); // 10000^(-e/1024)
    float ang = (float)p * rate;
    float s, c;
    sincosf(ang, &s, &c);
    pe[(size_t)(2 * dp) * HW_ + p]     = s;
    pe[(size_t)(2 * dp + 1) * HW_ + p] = c;
}

// ---------------- K1: q0[b,:] and v_cls[b,:] (wave per output row) ---------
__global__ void k_qv(const float* __restrict__ Wqkv, const float* __restrict__ bqkv,
                     const float* __restrict__ ctx,
                     float* __restrict__ q0, float* __restrict__ vcls) {
    int wid  = (blockIdx.x * 256 + threadIdx.x) >> 6;  // 0..16383
    int lane = threadIdx.x & 63;
    int isv  = wid >> 13;
    int r    = wid & 8191;
    int b = r >> 10, i = r & 1023;
    int row = isv ? (2 * D_ + i) : i;
    const float4* wr = (const float4*)(Wqkv + (size_t)row * D_);
    const float4* cb = (const float4*)(ctx + b * D_);
    float acc = 0.0f;
    for (int k = lane; k < 256; k += 64) {
        float4 a = wr[k], c = cb[k];
        acc += a.x * c.x + a.y * c.y + a.z * c.z + a.w * c.w;
    }
    for (int o = 32; o; o >>= 1) acc += __shfl_down(acc, o);
    if (lane == 0) {
        float v = acc + bqkv[row];
        if (isv) vcls[b * D_ + i] = v; else q0[b * D_ + i] = v;
    }
}

// ---------------- K2: u_t[b][d][h] (scale folded) and t_b[b][i] ------------
__global__ void k_u_tb(const float* __restrict__ Wqkv,
                       const float* __restrict__ Wo, const float* __restrict__ bo,
                       const float* __restrict__ q0, const float* __restrict__ vcls,
                       float* __restrict__ u_t, float* __restrict__ t_b) {
    if (blockIdx.x < 128) {
        int b = blockIdx.x >> 4, h = blockIdx.x & 15;
        int t = threadIdx.x;
        float a0 = 0, a1 = 0, a2 = 0, a3 = 0;
        const float* q0h = q0 + b * D_ + h * 64;
        for (int j = 0; j < 64; ++j) {
            float qj = q0h[j];
            const float* wr = Wqkv + (size_t)(D_ + h * 64 + j) * D_;
            a0 += qj * wr[t];
            a1 += qj * wr[t + 256];
            a2 += qj * wr[t + 512];
            a3 += qj * wr[t + 768];
        }
        float* ub = u_t + (size_t)(b * D_) * NH_ + h;
        ub[(size_t)t * 16]          = 0.125f * a0;
        ub[(size_t)(t + 256) * 16]  = 0.125f * a1;
        ub[(size_t)(t + 512) * 16]  = 0.125f * a2;
        ub[(size_t)(t + 768) * 16]  = 0.125f * a3;
    } else {
        int wid  = (blockIdx.x - 128) * 4 + (threadIdx.x >> 6);
        int lane = threadIdx.x & 63;
        int b = wid >> 10, i = wid & 1023;
        const float4* wr = (const float4*)(Wo + (size_t)i * D_);
        const float4* vb = (const float4*)(vcls + b * D_);
        float acc = 0.0f;
        for (int k = lane; k < 256; k += 64) {
            float4 a = wr[k], c = vb[k];
            acc += a.x * c.x + a.y * c.y + a.z * c.z + a.w * c.w;
        }
        for (int o = 32; o; o >>= 1) acc += __shfl_down(acc, o);
        if (lane == 0) t_b[b * D_ + i] = acc + bo[i];
    }
}

// ------- KA: scores + LN stats. grid (32,8): 128-p tile, b. block 1024. ----
// Each wave: d-slice of 64, 2 p per lane (float2). LDS reduce across 16 waves.
__global__ __launch_bounds__(1024) void k_scores(
        const float* __restrict__ x, const float* __restrict__ pe,
        const float* __restrict__ u_t, const float* __restrict__ t_b,
        float* __restrict__ scores, float* __restrict__ mu_o, float* __restrict__ rs_o) {
    int tid = threadIdx.x;
    int wave = tid >> 6, lane = tid & 63;
    int b = blockIdx.y;
    int pbase = blockIdx.x * 128;
    int p0 = pbase + lane * 2;
    const float* xb  = x  + (size_t)b * D_ * HW_ + p0;
    const float* peb = pe + p0;
    const float* tb  = t_b + b * D_;
    float acc0[16], acc1[16];
    #pragma unroll
    for (int h = 0; h < 16; ++h) { acc0[h] = 0.f; acc1[h] = 0.f; }
    float s0 = 0.f, s1 = 0.f, q0s = 0.f, q1s = 0.f;
    int dbeg = wave * 64;
    #pragma unroll 2
    for (int i = 0; i < 64; ++i) {
        int d = dbeg + i;
        float2 xv = *(const float2*)(xb  + (size_t)d * HW_);
        float2 pv = *(const float2*)(peb + (size_t)d * HW_);
        float xc0 = xv.x + pv.x, xc1 = xv.y + pv.y;
        float tbd = tb[d];
        float r0 = xc0 + tbd, r1 = xc1 + tbd;
        s0 += r0; s1 += r1; q0s += r0 * r0; q1s += r1 * r1;
        const float* up = u_t + ((size_t)(b * D_ + d) << 4);
        #pragma unroll
        for (int h = 0; h < 16; ++h) {
            float u = up[h];
            acc0[h] += u * xc0;
            acc1[h] += u * xc1;
        }
    }
    __shared__ float red[16][4][128];   // 32 KB
    #pragma unroll 1
    for (int c = 0; c < 4; ++c) {
        #pragma unroll
        for (int j = 0; j < 4; ++j) {
            red[wave][j][lane * 2]     = acc0[4 * c + j];
            red[wave][j][lane * 2 + 1] = acc1[4 * c + j];
        }
        __syncthreads();
        if (tid < 512) {
            int hh = tid >> 7, p = tid & 127;
            float s = 0.f;
            #pragma unroll
            for (int w2 = 0; w2 < 16; ++w2) s += red[w2][hh][p];
            scores[(size_t)(b * 16 + 4 * c + hh) * HW_ + pbase + p] = s;
        }
        __syncthreads();
    }
    red[wave][0][lane * 2]     = s0;
    red[wave][0][lane * 2 + 1] = s1;
    red[wave][1][lane * 2]     = q0s;
    red[wave][1][lane * 2 + 1] = q1s;
    __syncthreads();
    if (tid < 128) {
        float S = 0.f, Q = 0.f;
        #pragma unroll
        for (int w2 = 0; w2 < 16; ++w2) { S += red[w2][0][tid]; Q += red[w2][1][tid]; }
        float mu = S * (1.0f / 1024.0f);
        float var = Q * (1.0f / 1024.0f) - mu * mu;
        mu_o[b * HW_ + pbase + tid] = mu;
        rs_o[b * HW_ + pbase + tid] = rsqrtf(var + EPS_);
    }
}

// ---------------- KB: cls score + softmax over 4097 entries (in-place) ------
__global__ void k_softmax(const float* __restrict__ scores, const float* __restrict__ u_t,
                          const float* __restrict__ ctx,
                          float* __restrict__ probs_tok, float* __restrict__ probs0) {
    int b = blockIdx.x >> 4, h = blockIdx.x & 15;
    int t = threadIdx.x;  // 256
    __shared__ float lds[256];
    float part = 0.0f;
    for (int d = t; d < D_; d += 256)
        part += u_t[(size_t)(b * D_ + d) * 16 + h] * ctx[b * D_ + d];
    lds[t] = part; __syncthreads();
    for (int o = 128; o; o >>= 1) { if (t < o) lds[t] += lds[t + o]; __syncthreads(); }
    float s0 = lds[0];
    __syncthreads();
    const float4* sr = (const float4*)(scores + (size_t)(b * 16 + h) * HW_);
    float4 v[4];
    float m = s0;
    #pragma unroll
    for (int k = 0; k < 4; ++k) {
        v[k] = sr[t + 256 * k];
        m = fmaxf(m, fmaxf(fmaxf(v[k].x, v[k].y), fmaxf(v[k].z, v[k].w)));
    }
    lds[t] = m; __syncthreads();
    for (int o = 128; o; o >>= 1) { if (t < o) lds[t] = fmaxf(lds[t], lds[t + o]); __syncthreads(); }
    m = lds[0];
    __syncthreads();
    float zs = 0.0f;
    #pragma unroll
    for (int k = 0; k < 4; ++k) {
        v[k].x = expf(v[k].x - m); v[k].y = expf(v[k].y - m);
        v[k].z = expf(v[k].z - m); v[k].w = expf(v[k].w - m);
        zs += v[k].x + v[k].y + v[k].z + v[k].w;
    }
    float e0 = expf(s0 - m);
    lds[t] = zs; __syncthreads();
    for (int o = 128; o; o >>= 1) { if (t < o) lds[t] += lds[t + o]; __syncthreads(); }
    float inv = 1.0f / (lds[0] + e0);
    float4* pr = (float4*)(probs_tok + (size_t)(b * 16 + h) * HW_);
    #pragma unroll
    for (int k = 0; k < 4; ++k) {
        float4 o4 = v[k];
        o4.x *= inv; o4.y *= inv; o4.z *= inv; o4.w *= inv;
        pr[t + 256 * k] = o4;
    }
    if (t == 0) probs0[b * 16 + h] = e0 * inv;
}

// ------- KC: fused w-accumulate + LN feature-map write. grid (64,8), 256thr -
// wave handles 4 d-rows; lane strides p in float4.
__global__ __launch_bounds__(256) void k_wacc2(
        const float* __restrict__ x, const float* __restrict__ pe,
        const float* __restrict__ probs, const float* __restrict__ p0v,
        const float* __restrict__ ctx, const float* __restrict__ t_b,
        const float* __restrict__ mu_i, const float* __restrict__ rs_i,
        const float* __restrict__ gamma, const float* __restrict__ beta,
        float* __restrict__ w, float* __restrict__ out) {
    int wave = threadIdx.x >> 6, lane = threadIdx.x & 63;
    int b = blockIdx.y;
    int d0 = (blockIdx.x * 4 + wave) * 4;
    const float* xb = x + (size_t)b * D_ * HW_;
    const float* pb = probs + (size_t)b * 16 * HW_;
    float* ob = out + (size_t)b * D_ * HW_;
    float tbv[4], gv[4], bev[4];
    #pragma unroll
    for (int r = 0; r < 4; ++r) {
        tbv[r] = t_b[b * D_ + d0 + r];
        gv[r]  = gamma[d0 + r];
        bev[r] = beta[d0 + r];
    }
    float acc[4][16];
    #pragma unroll
    for (int r = 0; r < 4; ++r)
        #pragma unroll
        for (int h = 0; h < 16; ++h) acc[r][h] = 0.f;
    #pragma unroll 1
    for (int it = 0; it < 16; ++it) {
        int p = it * 256 + lane * 4;
        float4 xc4[4];
        #pragma unroll
        for (int r = 0; r < 4; ++r) {
            float4 xv = *(const float4*)(xb + (size_t)(d0 + r) * HW_ + p);
            float4 pv = *(const float4*)(pe + (size_t)(d0 + r) * HW_ + p);
            xc4[r].x = xv.x + pv.x; xc4[r].y = xv.y + pv.y;
            xc4[r].z = xv.z + pv.z; xc4[r].w = xv.w + pv.w;
        }
        float4 m4 = *(const float4*)(mu_i + b * HW_ + p);
        float4 r4 = *(const float4*)(rs_i + b * HW_ + p);
        #pragma unroll
        for (int r = 0; r < 4; ++r) {
            float4 o4;
            o4.x = (xc4[r].x + tbv[r] - m4.x) * r4.x * gv[r] + bev[r];
            o4.y = (xc4[r].y + tbv[r] - m4.y) * r4.y * gv[r] + bev[r];
            o4.z = (xc4[r].z + tbv[r] - m4.z) * r4.z * gv[r] + bev[r];
            o4.w = (xc4[r].w + tbv[r] - m4.w) * r4.w * gv[r] + bev[r];
            *(float4*)(ob + (size_t)(d0 + r) * HW_ + p) = o4;
        }
        #pragma unroll
        for (int h = 0; h < 16; ++h) {
            float4 pr = *(const float4*)(pb + (size_t)h * HW_ + p);
            #pragma unroll
            for (int r = 0; r < 4; ++r)
                acc[r][h] += pr.x * xc4[r].x + pr.y * xc4[r].y +
                             pr.z * xc4[r].z + pr.w * xc4[r].w;
        }
    }
    #pragma unroll
    for (int r = 0; r < 4; ++r)
        #pragma unroll
        for (int h = 0; h < 16; ++h) {
            float v = acc[r][h];
            for (int o = 32; o; o >>= 1) v += __shfl_down(v, o);
            acc[r][h] = v;
        }
    if (lane == 0) {
        #pragma unroll
        for (int h = 0; h < 16; ++h) {
            float pp = p0v[b * 16 + h];
            #pragma unroll
            for (int r = 0; r < 4; ++r)
                w[(size_t)(b * 16 + h) * D_ + d0 + r] = acc[r][h] + pp * ctx[b * D_ + d0 + r];
        }
    }
}

// ---------------- K7a: cls[b][i] = Wv[i,:] . w[b][i>>6][:] + bv -------------
__global__ void k_cls(const float* __restrict__ Wqkv, const float* __restrict__ bqkv,
                      const float* __restrict__ w, float* __restrict__ cls) {
    int wid  = (blockIdx.x * 256 + threadIdx.x) >> 6;
    int lane = threadIdx.x & 63;
    int b = wid >> 10, i = wid & 1023, h = i >> 6;
    const float4* wr = (const float4*)(Wqkv + (size_t)(2 * D_ + i) * D_);
    const float4* wb = (const float4*)(w + (size_t)(b * 16 + h) * D_);
    float acc = 0.0f;
    for (int k = lane; k < 256; k += 64) {
        float4 a = wr[k], c = wb[k];
        acc += a.x * c.x + a.y * c.y + a.z * c.z + a.w * c.w;
    }
    for (int o = 32; o; o >>= 1) acc += __shfl_down(acc, o);
    if (lane == 0) cls[b * D_ + i] = acc + bqkv[2 * D_ + i];
}

// ---------------- K7b: res0 = Wo @ cls + bo + ctx ---------------------------
__global__ void k_attn0(const float* __restrict__ Wo, const float* __restrict__ bo,
                        const float* __restrict__ cls, const float* __restrict__ ctx,
                        float* __restrict__ res0) {
    int wid  = (blockIdx.x * 256 + threadIdx.x) >> 6;
    int lane = threadIdx.x & 63;
    int b = wid >> 10, i = wid & 1023;
    const float4* wr = (const float4*)(Wo + (size_t)i * D_);
    const float4* cb = (const float4*)(cls + b * D_);
    float acc = 0.0f;
    for (int k = lane; k < 256; k += 64) {
        float4 a = wr[k], c = cb[k];
        acc += a.x * c.x + a.y * c.y + a.z * c.z + a.w * c.w;
    }
    for (int o = 32; o; o >>= 1) acc += __shfl_down(acc, o);
    if (lane == 0) res0[b * D_ + i] = acc + bo[i] + ctx[b * D_ + i];
}

// ---------------- K7c: LayerNorm of res0 -> context_token_out ---------------
__global__ void k_ln0(const float* __restrict__ res0, const float* __restrict__ gamma,
                      const float* __restrict__ beta, float* __restrict__ out) {
    int b = blockIdx.x, t = threadIdx.x;
    __shared__ float lds[512];
    float v[4];
    float s = 0.0f, sq = 0.0f;
    #pragma unroll
    for (int k = 0; k < 4; ++k) {
        v[k] = res0[b * D_ + t + 256 * k];
        s += v[k]; sq += v[k] * v[k];
    }
    lds[t] = s; lds[256 + t] = sq; __syncthreads();
    for (int o = 128; o; o >>= 1) {
        if (t < o) { lds[t] += lds[t + o]; lds[256 + t] += lds[256 + t + o]; }
        __syncthreads();
    }
    float mu = lds[0] * (1.0f / D_);
    float var = lds[256] * (1.0f / D_) - mu * mu;
    float rstd = rsqrtf(var + EPS_);
    #pragma unroll
    for (int k = 0; k < 4; ++k) {
        int i = t + 256 * k;
        out[(size_t)B_ * D_ * HW_ + b * D_ + i] = (v[k] - mu) * rstd * gamma[i] + beta[i];
    }
}

extern "C" void kernel_launch(void* const* d_in, const int* in_sizes, int n_in,
                              void* d_out, int out_size, void* d_ws, size_t ws_size,
                              hipStream_t stream) {
    const float* x     = (const float*)d_in[0];
    const float* ctx   = (const float*)d_in[1];
    const float* Wqkv  = (const float*)d_in[2];
    const float* bqkv  = (const float*)d_in[3];
    const float* Wo    = (const float*)d_in[4];
    const float* bo    = (const float*)d_in[5];
    const float* gamma = (const float*)d_in[6];
    const float* beta  = (const float*)d_in[7];
    float* out = (float*)d_out;
    float* ws  = (float*)d_ws;

    float* pe   = ws + PE_OFF;
    float* u_t  = ws + UT_OFF;
    float* t_b  = ws + TB_OFF;
    float* sc   = ws + SC_OFF;   // scores, then probs in-place
    float* q0   = ws + Q0_OFF;
    float* vcls = ws + VCLS_OFF;
    float* p0   = ws + P0_OFF;
    float* mu   = ws + MU_OFF;
    float* rs   = ws + RS_OFF;
    float* w    = ws + W_OFF;
    float* cls  = ws + CLS_OFF;
    float* r0   = ws + R0_OFF;

    k_pe<<<dim3(8192), dim3(256), 0, stream>>>(pe);
    k_qv<<<dim3(4096), dim3(256), 0, stream>>>(Wqkv, bqkv, ctx, q0, vcls);
    k_u_tb<<<dim3(2176), dim3(256), 0, stream>>>(Wqkv, Wo, bo, q0, vcls, u_t, t_b);
    k_scores<<<dim3(32, 8), dim3(1024), 0, stream>>>(x, pe, u_t, t_b, sc, mu, rs);
    k_softmax<<<dim3(128), dim3(256), 0, stream>>>(sc, u_t, ctx, sc, p0);
    k_wacc2<<<dim3(64, 8), dim3(256), 0, stream>>>(x, pe, sc, p0, ctx, t_b, mu, rs,
                                                   gamma, beta, w, out);
    k_cls<<<dim3(2048), dim3(256), 0, stream>>>(Wqkv, bqkv, w, cls);
    k_attn0<<<dim3(2048), dim3(256), 0, stream>>>(Wo, bo, cls, ctx, r0);
    k_ln0<<<dim3(8), dim3(256), 0, stream>>>(r0, gamma, beta, out);
}